// Round 1
// baseline (20831.273 us; speedup 1.0000x reference)
//
#include <hip/hip_runtime.h>
#include <hip/hip_fp16.h>

// LSTM T=512 B=64 D=256 H=256, fp32 in/out.
// Design: one workgroup (1024 threads) per batch element; each thread owns one
// of the 4H=1024 gate columns, with its 512-element (x||h) f16 weight column
// resident in 256 VGPRs. Per step: broadcast x_t||h_{t-1} (f16, 1KB) from LDS,
// 256 v_dot2_f32_f16 per thread, activation, gate-combine via LDS, h update by
// threads 0..255. Sequential T loop inside the kernel; __syncthreads per step.

#define T_STEPS 512
#define BATCH   64
#define DIM     256
#define HID     256

typedef _Float16 half2_t __attribute__((ext_vector_type(2)));

__device__ __forceinline__ half2_t bc_f32(float f) {
    half2_t r;
    __builtin_memcpy(&r, &f, 4);
    return r;
}

__device__ __forceinline__ float dot2acc(half2_t a, half2_t b, float c) {
#if __has_builtin(__builtin_amdgcn_fdot2)
    return __builtin_amdgcn_fdot2(a, b, c, false);
#else
    return c + (float)a.x * (float)b.x + (float)a.y * (float)b.y;
#endif
}

__device__ __forceinline__ float fast_sigmoid(float x) {
    return 1.0f / (1.0f + __expf(-x));
}
__device__ __forceinline__ float fast_tanh(float x) {
    // tanh(x) = 2*sigmoid(2x) - 1
    return 2.0f / (1.0f + __expf(-2.0f * x)) - 1.0f;
}

__global__ void __launch_bounds__(1024) lstm_fused_kernel(
    const float* __restrict__ X,
    const float* __restrict__ Wax, const float* __restrict__ Wix,
    const float* __restrict__ Wfx, const float* __restrict__ Wox,
    const float* __restrict__ Wah, const float* __restrict__ Wih,
    const float* __restrict__ Wfh, const float* __restrict__ Woh,
    const float* __restrict__ ba,  const float* __restrict__ bi,
    const float* __restrict__ bf,  const float* __restrict__ bo,
    float* __restrict__ out)
{
    const int b    = blockIdx.x;      // batch element
    const int tid  = threadIdx.x;     // 0..1023, gate column
    const int gate = tid >> 8;        // 0:a(tanh) 1:i 2:f 3:o
    const int j    = tid & 255;       // hidden unit within gate

    __shared__ __align__(16) _Float16 xh[512];   // [x_t (256) | h_{t-1} (256)]
    __shared__ float act[1024];                  // activated gate values

    const float* Wxg = (gate == 0) ? Wax : (gate == 1) ? Wix : (gate == 2) ? Wfx : Wox;
    const float* Whg = (gate == 0) ? Wah : (gate == 1) ? Wih : (gate == 2) ? Wfh : Woh;
    const float* bg  = (gate == 0) ? ba  : (gate == 1) ? bi  : (gate == 2) ? bf  : bo;

    // ---- Preload this thread's weight column into registers (f16 packed) ----
    // w[0..127]   : Wx column (rows 0..255, pairs)
    // w[128..255] : Wh column (rows 0..255, pairs)
    half2_t w[256];
#pragma unroll
    for (int k = 0; k < 128; ++k) {
        float a0 = Wxg[(2 * k)     * HID + j];
        float a1 = Wxg[(2 * k + 1) * HID + j];
        half2_t p; p.x = (_Float16)a0; p.y = (_Float16)a1;
        w[k] = p;
        float c0 = Whg[(2 * k)     * HID + j];
        float c1 = Whg[(2 * k + 1) * HID + j];
        half2_t q; q.x = (_Float16)c0; q.y = (_Float16)c1;
        w[128 + k] = q;
    }
    const float bias = bg[j];

    // ---- Init: h0 = 0, load x_0 ----
    if (tid < 256) {
        xh[256 + tid] = (_Float16)0.0f;
    } else if (tid < 512) {
        xh[tid - 256] = (_Float16)X[(size_t)0 * BATCH * DIM + (size_t)b * DIM + (tid - 256)];
    }
    float s = 0.0f;  // cell state (meaningful for tid < 256)
    __syncthreads();

    const float4* xh4 = (const float4*)xh;

    for (int t = 0; t < T_STEPS; ++t) {
        // Prefetch next x early so HBM/L3 latency hides under the dot loop.
        float xnext = 0.0f;
        if (tid >= 256 && tid < 512 && t + 1 < T_STEPS) {
            xnext = X[(size_t)(t + 1) * BATCH * DIM + (size_t)b * DIM + (tid - 256)];
        }

        // g[col] = bias + dot(x_t, Wx[:,col]) + dot(h_{t-1}, Wh[:,col])
        float acc = bias;
#pragma unroll
        for (int i = 0; i < 64; ++i) {
            float4 v = xh4[i];   // 8 f16 (uniform address -> LDS broadcast)
            acc = dot2acc(bc_f32(v.x), w[4 * i + 0], acc);
            acc = dot2acc(bc_f32(v.y), w[4 * i + 1], acc);
            acc = dot2acc(bc_f32(v.z), w[4 * i + 2], acc);
            acc = dot2acc(bc_f32(v.w), w[4 * i + 3], acc);
        }

        float av = (gate == 0) ? fast_tanh(acc) : fast_sigmoid(acc);
        act[tid] = av;
        __syncthreads();   // act ready; xh free to overwrite

        if (tid < 256) {
            float aa = act[j];
            float ii = act[256 + j];
            float ff = act[512 + j];
            float oo = act[768 + j];
            s = aa * ii + s * ff;
            float h = fast_tanh(s) * oo;
            out[(size_t)t * BATCH * HID + (size_t)b * HID + j] = h;
            xh[256 + j] = (_Float16)h;
        } else if (tid < 512 && t + 1 < T_STEPS) {
            xh[tid - 256] = (_Float16)xnext;
        }
        __syncthreads();   // xh ready for step t+1
    }
}

extern "C" void kernel_launch(void* const* d_in, const int* in_sizes, int n_in,
                              void* d_out, int out_size, void* d_ws, size_t ws_size,
                              hipStream_t stream) {
    const float* X   = (const float*)d_in[0];
    const float* Wax = (const float*)d_in[1];
    const float* Wix = (const float*)d_in[2];
    const float* Wfx = (const float*)d_in[3];
    const float* Wox = (const float*)d_in[4];
    const float* Wah = (const float*)d_in[5];
    const float* Wih = (const float*)d_in[6];
    const float* Wfh = (const float*)d_in[7];
    const float* Woh = (const float*)d_in[8];
    const float* ba  = (const float*)d_in[9];
    const float* bi  = (const float*)d_in[10];
    const float* bf  = (const float*)d_in[11];
    const float* bo  = (const float*)d_in[12];
    float* out = (float*)d_out;

    lstm_fused_kernel<<<dim3(BATCH), dim3(1024), 0, stream>>>(
        X, Wax, Wix, Wfx, Wox, Wah, Wih, Wfh, Woh, ba, bi, bf, bo, out);
}

// Round 2
// 3933.962 us; speedup vs baseline: 5.2952x; 5.2952x over previous
//
#include <hip/hip_runtime.h>
#include <hip/hip_fp16.h>

// LSTM T=512 B=64 D=256 H=256, fp32 in/out.
//
// Phase 0: convert X to f16; build transposed f16 weights Wxt/Wht [4H][K].
// Phase 1: gx = X @ Wx via MFMA f16 GEMM (M=32768, K=256, N=1024) -> ws (f16).
// Phase 2: recurrence, 1 CU per batch element. Wh (512 KB f16) resident:
//          192 elems/column in VGPRs (512t x 2 cols x 96 half2 = 384 KB)
//          + 64 elems/column in LDS (128 KB, lane-contiguous -> conflict-free).
//          h broadcast via LDS; per-step cost ~ 1024 VALU cyc/SIMD.

#define T_STEPS 512
#define BATCH   64
#define HID     256
#define G4      1024                  // 4*HID
#define GM      (T_STEPS * BATCH)     // 32768

typedef _Float16 half2_t __attribute__((ext_vector_type(2)));
typedef _Float16 f16x8   __attribute__((ext_vector_type(8)));
typedef float    f32x4   __attribute__((ext_vector_type(4)));

// ws element offsets (f16 elements)
#define XH_OFF  0u          // [32768][256]  f16   8,388,608
#define WXT_OFF 8388608u    // [1024][256]   f16     262,144
#define WHT_OFF 8650752u    // [1024][256]   f16     262,144
#define GX_OFF  8912896u    // [32768][1024] f16  33,554,432  (total 84.9 MB)

__device__ __forceinline__ half2_t bc_f32(float f) {
    half2_t r; __builtin_memcpy(&r, &f, 4); return r;
}
__device__ __forceinline__ half2_t bc_u32(unsigned u) {
    half2_t r; __builtin_memcpy(&r, &u, 4); return r;
}
__device__ __forceinline__ float dot2acc(half2_t a, half2_t b, float c) {
#if __has_builtin(__builtin_amdgcn_fdot2)
    return __builtin_amdgcn_fdot2(a, b, c, false);
#else
    return c + (float)a.x * (float)b.x + (float)a.y * (float)b.y;
#endif
}
__device__ __forceinline__ float fast_sigmoid(float x) {
    return 1.0f / (1.0f + __expf(-x));
}
__device__ __forceinline__ float fast_tanh(float x) {
    return 2.0f / (1.0f + __expf(-2.0f * x)) - 1.0f;
}

// ---------------- Phase 0a: X f32 -> f16 ----------------
__global__ __launch_bounds__(256) void k_prep_x(const float* __restrict__ X,
                                                _Float16* __restrict__ Xh) {
    const int i = blockIdx.x * 256 + threadIdx.x;   // x4 floats
    float4 v = ((const float4*)X)[i];
    half2_t a; a.x = (_Float16)v.x; a.y = (_Float16)v.y;
    half2_t b; b.x = (_Float16)v.z; b.y = (_Float16)v.w;
    ((half2_t*)Xh)[2 * i]     = a;
    ((half2_t*)Xh)[2 * i + 1] = b;
}

// ---------------- Phase 0b: transpose weights to [4H][K] f16 ----------------
__global__ __launch_bounds__(256) void k_prep_w(
    const float* __restrict__ Wax, const float* __restrict__ Wix,
    const float* __restrict__ Wfx, const float* __restrict__ Wox,
    const float* __restrict__ Wah, const float* __restrict__ Wih,
    const float* __restrict__ Wfh, const float* __restrict__ Woh,
    _Float16* __restrict__ Wxt, _Float16* __restrict__ Wht)
{
    const int id  = blockIdx.x * 256 + threadIdx.x;   // [0, 524288)
    const int mat = id >> 18;                          // 0: Wx, 1: Wh
    const int idx = id & 262143;
    const int k   = idx >> 10;                         // [0,256)
    const int c   = idx & 1023;                        // gate column
    const int g   = c >> 8;
    const int j   = c & 255;
    const float* src;
    if (mat == 0) src = (g == 0) ? Wax : (g == 1) ? Wix : (g == 2) ? Wfx : Wox;
    else          src = (g == 0) ? Wah : (g == 1) ? Wih : (g == 2) ? Wfh : Woh;
    _Float16* dst = mat ? Wht : Wxt;
    dst[c * 256 + k] = (_Float16)src[k * 256 + j];
}

// ---------------- Phase 1: gx = Xh @ Wxt^T (both row-major contiguous-K) ----
// M=32768, N=1024, K=256. Block 256 thr = 4 waves; tile 128(M) x 64(N).
// Wave w: rows [bx*128 + w*32, +32), cols [by*64, +64). Direct-from-global.
__global__ __launch_bounds__(256) void k_gemm(const _Float16* __restrict__ Xh,
                                              const _Float16* __restrict__ Wxt,
                                              _Float16* __restrict__ gx)
{
    const int lane = threadIdx.x & 63, wave = threadIdx.x >> 6;
    const int rowbase = blockIdx.x * 128 + wave * 32;
    const int colbase = blockIdx.y * 64;
    const int r15 = lane & 15, kg = lane >> 4;   // kgroup 0..3 (8 k each)

    f32x4 acc[2][4] = {};
    const _Float16* ap0 = Xh  + (size_t)(rowbase + r15) * 256 + kg * 8;
    const _Float16* ap1 = ap0 + 16 * 256;
    const _Float16* bp  = Wxt + (size_t)(colbase + r15) * 256 + kg * 8;

#pragma unroll
    for (int ks = 0; ks < 8; ++ks) {
        f16x8 a0 = *(const f16x8*)(ap0 + ks * 32);
        f16x8 a1 = *(const f16x8*)(ap1 + ks * 32);
        f16x8 b0 = *(const f16x8*)(bp  + ks * 32);
        f16x8 b1 = *(const f16x8*)(bp  + 16 * 256 + ks * 32);
        f16x8 b2 = *(const f16x8*)(bp  + 32 * 256 + ks * 32);
        f16x8 b3 = *(const f16x8*)(bp  + 48 * 256 + ks * 32);
        acc[0][0] = __builtin_amdgcn_mfma_f32_16x16x32_f16(a0, b0, acc[0][0], 0, 0, 0);
        acc[0][1] = __builtin_amdgcn_mfma_f32_16x16x32_f16(a0, b1, acc[0][1], 0, 0, 0);
        acc[0][2] = __builtin_amdgcn_mfma_f32_16x16x32_f16(a0, b2, acc[0][2], 0, 0, 0);
        acc[0][3] = __builtin_amdgcn_mfma_f32_16x16x32_f16(a0, b3, acc[0][3], 0, 0, 0);
        acc[1][0] = __builtin_amdgcn_mfma_f32_16x16x32_f16(a1, b0, acc[1][0], 0, 0, 0);
        acc[1][1] = __builtin_amdgcn_mfma_f32_16x16x32_f16(a1, b1, acc[1][1], 0, 0, 0);
        acc[1][2] = __builtin_amdgcn_mfma_f32_16x16x32_f16(a1, b2, acc[1][2], 0, 0, 0);
        acc[1][3] = __builtin_amdgcn_mfma_f32_16x16x32_f16(a1, b3, acc[1][3], 0, 0, 0);
    }
    // C/D layout (m89-verified): col = lane&15, row = (lane>>4)*4 + r
#pragma unroll
    for (int mt = 0; mt < 2; ++mt)
#pragma unroll
        for (int nt = 0; nt < 4; ++nt)
#pragma unroll
            for (int r = 0; r < 4; ++r) {
                int row = rowbase + mt * 16 + kg * 4 + r;
                int col = colbase + nt * 16 + r15;
                gx[(size_t)row * G4 + col] = (_Float16)acc[mt][nt][r];
            }
}

// ---------------- Phase 2: recurrence ----------------
// 64 blocks x 512 threads (8 waves, 2/SIMD, 256-VGPR cap).
// Thread owns gate-columns c0=tid, c1=tid+512.
// Wh column (K=256 f16): pairs 0..95 in VGPRs, pairs 96..127 in LDS.
__global__ __launch_bounds__(512, 2) void k_recur(
    const _Float16* __restrict__ Wht, const _Float16* __restrict__ gx,
    const float* __restrict__ ba, const float* __restrict__ bi,
    const float* __restrict__ bf_, const float* __restrict__ bo,
    float* __restrict__ out)
{
    const int b = blockIdx.x, tid = threadIdx.x;
    const int j = tid & 255;
    const int c0 = tid, c1 = tid + 512;

    __shared__ uint4 wl[16 * 512];                 // 128 KB weight tail
    __shared__ float act[1024];                    // 4 KB
    __shared__ __align__(16) _Float16 hbuf[256];   // 512 B

    // ---- load resident weights ----
    half2_t w0[96], w1[96];
    {
        const half2_t* s0 = (const half2_t*)(Wht + (size_t)c0 * 256);
        const half2_t* s1 = (const half2_t*)(Wht + (size_t)c1 * 256);
#pragma unroll
        for (int p = 0; p < 96; ++p) { w0[p] = s0[p]; w1[p] = s1[p]; }
        const uint4* q0 = (const uint4*)(Wht + (size_t)c0 * 256 + 192);
        const uint4* q1 = (const uint4*)(Wht + (size_t)c1 * 256 + 192);
#pragma unroll
        for (int i = 0; i < 8; ++i) {
            wl[i * 512 + tid]       = q0[i];       // col0 pairs 96+4i..+3
            wl[(8 + i) * 512 + tid] = q1[i];       // col1 pairs 96+4i..+3
        }
    }
    const float bias0 = ((tid >> 8) == 0 ? ba  : bi)[j];
    const float bias1 = ((tid >> 8) == 0 ? bf_ : bo)[j];

    if (tid < 256) hbuf[tid] = (_Float16)0.0f;
    float s = 0.0f;
    _Float16 gc0 = gx[(size_t)b * G4 + c0];
    _Float16 gc1 = gx[(size_t)b * G4 + c1];
    __syncthreads();

    const float4* h4 = (const float4*)hbuf;

#pragma unroll 1
    for (int t = 0; t < T_STEPS; ++t) {
        // prefetch next-step gx early (covers L2/L3 latency under the dot)
        _Float16 gn0 = (_Float16)0.0f, gn1 = (_Float16)0.0f;
        if (t + 1 < T_STEPS) {
            const size_t m = (size_t)(t + 1) * BATCH + b;
            gn0 = gx[m * G4 + c0];
            gn1 = gx[m * G4 + c1];
        }

        float acc0 = bias0 + (float)gc0;
        float acc1 = bias1 + (float)gc1;

#pragma unroll
        for (int i2 = 0; i2 < 24; ++i2) {          // pairs 0..95 (registers)
            float4 hv = h4[i2];                     // uniform -> broadcast
            half2_t hp0 = bc_f32(hv.x), hp1 = bc_f32(hv.y);
            half2_t hp2 = bc_f32(hv.z), hp3 = bc_f32(hv.w);
            acc0 = dot2acc(hp0, w0[4 * i2 + 0], acc0);
            acc1 = dot2acc(hp0, w1[4 * i2 + 0], acc1);
            acc0 = dot2acc(hp1, w0[4 * i2 + 1], acc0);
            acc1 = dot2acc(hp1, w1[4 * i2 + 1], acc1);
            acc0 = dot2acc(hp2, w0[4 * i2 + 2], acc0);
            acc1 = dot2acc(hp2, w1[4 * i2 + 2], acc1);
            acc0 = dot2acc(hp3, w0[4 * i2 + 3], acc0);
            acc1 = dot2acc(hp3, w1[4 * i2 + 3], acc1);
        }
#pragma unroll
        for (int i2 = 0; i2 < 8; ++i2) {            // pairs 96..127 (LDS)
            float4 hv = h4[24 + i2];
            uint4 wa = wl[i2 * 512 + tid];          // lane-contiguous, no conflicts
            uint4 wb = wl[(8 + i2) * 512 + tid];
            acc0 = dot2acc(bc_f32(hv.x), bc_u32(wa.x), acc0);
            acc1 = dot2acc(bc_f32(hv.x), bc_u32(wb.x), acc1);
            acc0 = dot2acc(bc_f32(hv.y), bc_u32(wa.y), acc0);
            acc1 = dot2acc(bc_f32(hv.y), bc_u32(wb.y), acc1);
            acc0 = dot2acc(bc_f32(hv.z), bc_u32(wa.z), acc0);
            acc1 = dot2acc(bc_f32(hv.z), bc_u32(wb.z), acc1);
            acc0 = dot2acc(bc_f32(hv.w), bc_u32(wa.w), acc0);
            acc1 = dot2acc(bc_f32(hv.w), bc_u32(wb.w), acc1);
        }

        float av0 = (tid < 256) ? fast_tanh(acc0) : fast_sigmoid(acc0);
        float av1 = fast_sigmoid(acc1);
        act[c0] = av0;
        act[c1] = av1;
        __syncthreads();

        if (tid < 256) {
            float aa = act[tid], ii = act[tid + 256];
            float ff = act[tid + 512], oo = act[tid + 768];
            s = aa * ii + s * ff;
            float h = fast_tanh(s) * oo;
            out[((size_t)t * BATCH + b) * HID + tid] = h;
            hbuf[tid] = (_Float16)h;
        }
        __syncthreads();
        gc0 = gn0; gc1 = gn1;
    }
}

extern "C" void kernel_launch(void* const* d_in, const int* in_sizes, int n_in,
                              void* d_out, int out_size, void* d_ws, size_t ws_size,
                              hipStream_t stream) {
    const float* X   = (const float*)d_in[0];
    const float* Wax = (const float*)d_in[1];
    const float* Wix = (const float*)d_in[2];
    const float* Wfx = (const float*)d_in[3];
    const float* Wox = (const float*)d_in[4];
    const float* Wah = (const float*)d_in[5];
    const float* Wih = (const float*)d_in[6];
    const float* Wfh = (const float*)d_in[7];
    const float* Woh = (const float*)d_in[8];
    const float* ba  = (const float*)d_in[9];
    const float* bi  = (const float*)d_in[10];
    const float* bf  = (const float*)d_in[11];
    const float* bo  = (const float*)d_in[12];

    _Float16* ws  = (_Float16*)d_ws;
    _Float16* Xh  = ws + XH_OFF;
    _Float16* Wxt = ws + WXT_OFF;
    _Float16* Wht = ws + WHT_OFF;
    _Float16* gxp = ws + GX_OFF;

    k_prep_x<<<dim3(GM * 256 / 4 / 256), dim3(256), 0, stream>>>(X, Xh);
    k_prep_w<<<dim3(2048), dim3(256), 0, stream>>>(Wax, Wix, Wfx, Wox,
                                                   Wah, Wih, Wfh, Woh, Wxt, Wht);
    k_gemm<<<dim3(GM / 128, G4 / 64), dim3(256), 0, stream>>>(Xh, Wxt, gxp);
    k_recur<<<dim3(BATCH), dim3(512), 0, stream>>>(Wht, gxp, ba, bi, bf, bo,
                                                   (float*)d_out);
}